// Round 1
// 253.324 us; speedup vs baseline: 1.1564x; 1.1564x over previous
//
#include <hip/hip_runtime.h>
#include <math.h>

// ---------- problem constants ----------
#define BB 4
#define SS 4096
#define EE 1024
#define HH 16
#define DD 64
#define MM (BB*SS)          // 16384 rows

typedef _Float16 f16x8 __attribute__((ext_vector_type(8)));
typedef _Float16 f16x4 __attribute__((ext_vector_type(4)));
typedef float    f32x4 __attribute__((ext_vector_type(4)));

typedef __attribute__((address_space(3))) void lds_void;
typedef __attribute__((address_space(1))) void gm_void;

__device__ __forceinline__ void gload16(const void* g, void* l) {
  // async global->LDS, 16B per lane; LDS dest is wave-uniform base + lane*16
  __builtin_amdgcn_global_load_lds((gm_void*)g, (lds_void*)l, 16, 0, 0);
}

// ---------- conversion kernels ----------
__global__ __launch_bounds__(256) void conv_x_kernel(const float* __restrict__ x,
                                                     _Float16* __restrict__ xh, int n4) {
  int i = blockIdx.x * blockDim.x + threadIdx.x;
  int stride = gridDim.x * blockDim.x;
  for (; i < n4; i += stride) {
    f32x4 v = *(const f32x4*)&x[(size_t)i * 4];
    f16x4 h;
    h[0] = (_Float16)v[0]; h[1] = (_Float16)v[1];
    h[2] = (_Float16)v[2]; h[3] = (_Float16)v[3];
    *(f16x4*)&xh[(size_t)i * 4] = h;
  }
}

__global__ __launch_bounds__(256) void conv_w_kernel(const float* __restrict__ Wq,
                                                     const float* __restrict__ Wk,
                                                     const float* __restrict__ Wv,
                                                     const float* __restrict__ Wo,
                                                     _Float16* __restrict__ wqkv,
                                                     _Float16* __restrict__ woh) {
  const int per = (EE * EE) / 4;  // float4s per matrix = 262144
  int i = blockIdx.x * blockDim.x + threadIdx.x;
  int stride = gridDim.x * blockDim.x;
  for (; i < 4 * per; i += stride) {
    int seg = i / per, off = i - seg * per;
    const float* src = (seg == 0) ? Wq : (seg == 1) ? Wk : (seg == 2) ? Wv : Wo;
    _Float16* dst = (seg < 3) ? (wqkv + (size_t)seg * EE * EE) : woh;
    f32x4 v = *(const f32x4*)&src[(size_t)off * 4];
    f16x4 h;
    h[0] = (_Float16)v[0]; h[1] = (_Float16)v[1];
    h[2] = (_Float16)v[2]; h[3] = (_Float16)v[3];
    *(f16x4*)&dst[(size_t)off * 4] = h;
  }
}

// ---------- 256x256 8-phase fp16 MFMA GEMM (T1+T2+T3+T4+T5) ----------
// C[m][n] = sum_k A[m][k]*B[n][k], K = 1024 (16 K-tiles of BK=64).
// 512 threads = 8 waves (2 Mx4 N); per-wave output 128x64; acc[8][4] f32x4.
// LDS 128 KiB: A,B each 2 bufs x 256x64 f16, st_16x32 swizzled subtiles.
// Stage pipeline: each phase stages one 16KB half-tile (2 x gload16/wave);
// boundary waits are counted vmcnt(6) (3 half-tiles always in flight).

#define SB0() __builtin_amdgcn_sched_barrier(0)
#define VMW6 asm volatile("s_waitcnt vmcnt(6)" ::: "memory")
#define VMW0 asm volatile("s_waitcnt vmcnt(0)" ::: "memory")
#define NOP_ do {} while (0)

// stage one half-tile (128 rows x 64 k) of matrix at Gbase into its LDS ring.
// per wave: subtiles (rg*2+kgs) and (rg*2+kgs+8); dest linear, src pre-swizzled.
#define STAGE_M(Gb, Lb, t, hf) do {                                          \
    const char* g_ = (Gb) + ((size_t)(hf) << 18) + (size_t)(t) * 128;        \
    char* d_ = (Lb) + (((t) & 1) << 15) + ((hf) << 14) + dsub;               \
    gload16(g_, d_);                                                         \
    gload16(g_ + ((size_t)64 << 11), d_ + 8192);                             \
  } while (0)

#define STAGE_A(t, hf) STAGE_M(Ag, Asb, t, hf)
#define STAGE_B(t, hf) STAGE_M(Bg, Bsb, t, hf)

// swizzled ds reads: rowgroup*2048 + kslice*1024 + lane offset (lof has the XOR)
#define RD_A(mf, s) (*(const f16x8*)(Asb + buf_ +                            \
    (((((mf) < 4) ? 0 : 8) + wr4 + ((mf) & 3)) << 11) + ((s) << 10) + lof))
#define RD_B(nf, s) (*(const f16x8*)(Bsb + buf_ + ((wc4 + (nf)) << 11) + ((s) << 10) + lof))

#define PHASE(t, P, STG, VMC) do {                                           \
    const int buf_ = ((t) & 1) << 15;                                        \
    if ((P) == 0) {                                                          \
      _Pragma("unroll") for (int nf = 0; nf < 4; nf++) {                     \
        b[nf][0] = RD_B(nf, 0); b[nf][1] = RD_B(nf, 1);                      \
      }                                                                      \
    }                                                                        \
    aP[0][0] = RD_A((P) * 2, 0);     aP[0][1] = RD_A((P) * 2, 1);            \
    aP[1][0] = RD_A((P) * 2 + 1, 0); aP[1][1] = RD_A((P) * 2 + 1, 1);        \
    STG;                                                                     \
    SB0(); __builtin_amdgcn_s_barrier(); SB0();                              \
    asm volatile("s_waitcnt lgkmcnt(0)" ::: "memory"); SB0();                \
    __builtin_amdgcn_s_setprio(1);                                           \
    _Pragma("unroll") for (int nf = 0; nf < 4; nf++) {                       \
      acc[(P)*2][nf]   = __builtin_amdgcn_mfma_f32_16x16x32_f16(aP[0][0], b[nf][0], acc[(P)*2][nf], 0, 0, 0);   \
      acc[(P)*2][nf]   = __builtin_amdgcn_mfma_f32_16x16x32_f16(aP[0][1], b[nf][1], acc[(P)*2][nf], 0, 0, 0);   \
      acc[(P)*2+1][nf] = __builtin_amdgcn_mfma_f32_16x16x32_f16(aP[1][0], b[nf][0], acc[(P)*2+1][nf], 0, 0, 0); \
      acc[(P)*2+1][nf] = __builtin_amdgcn_mfma_f32_16x16x32_f16(aP[1][1], b[nf][1], acc[(P)*2+1][nf], 0, 0, 0); \
    }                                                                        \
    __builtin_amdgcn_s_setprio(0);                                           \
    VMC;                                                                     \
    SB0(); __builtin_amdgcn_s_barrier(); SB0();                              \
  } while (0)

// per K-tile: 4 phases; stages: ph1 A1(t+1), ph2 B0(t+2), ph3 B1(t+2), ph4 A0(t+2)
#define TILE(t, S1, S2, S3, S4, VMC) do {                                    \
    PHASE(t, 0, S1, NOP_);                                                   \
    PHASE(t, 1, S2, NOP_);                                                   \
    PHASE(t, 2, S3, NOP_);                                                   \
    PHASE(t, 3, S4, VMC);                                                    \
  } while (0)

template <int EPI>
__global__ __launch_bounds__(512, 2) void gemm256(const _Float16* __restrict__ A,
                                                  const _Float16* __restrict__ Bw,
                                                  const float* __restrict__ bias0,
                                                  const float* __restrict__ bias1,
                                                  const float* __restrict__ bias2,
                                                  _Float16* __restrict__ O0,
                                                  _Float16* __restrict__ O1,
                                                  _Float16* __restrict__ O2,
                                                  float* __restrict__ OF) {
  __shared__ __align__(16) char lds[131072];
  char* Asb = lds;            // 2 bufs x 32KB
  char* Bsb = lds + 65536;    // 2 bufs x 32KB

  const int tid  = threadIdx.x;
  const int lane = tid & 63;
  const int wv   = tid >> 6;           // 0..7
  const int wr4  = (wv >> 2) << 2;     // wr*4 (rowgroup offset)
  const int wc4  = (wv & 3) << 2;      // wc*4
  const int wrow = (wv >> 2) << 6;     // wr*64
  const int wcol = (wv & 3) << 6;      // wc*64

  // T1: bijective XCD swizzle (gridDim.x % 8 == 0 for both instantiations)
  constexpr int NX = (EPI == 0) ? 12 : 4;
  const int q = (int)gridDim.x >> 3;
  const int bid = (int)blockIdx.x;
  const int sid = (bid & 7) * q + (bid >> 3);
  const int mbase = (sid / NX) << 8;
  const int nbase = (sid % NX) << 8;

  // per-lane ds-read offset with st_16x32 swizzle: (fr*64 + kg*16) ^ ((fr&8)<<2)
  const int lof   = (((lane & 15) << 6) | ((lane >> 4) << 4)) ^ ((lane & 8) << 2);
  // per-lane stage-source offsets (inverse swizzle folded into global address)
  const int srow  = lane >> 2;
  const int sbyte = ((lane & 3) << 4) ^ (lane & 32);

  const int rg   = wv >> 1;            // wave's rowgroup within half-tile
  const int kgs  = wv & 1;             // wave's k-group
  const int dsub = ((rg << 1) + kgs) << 10;

  const char* Ag = (const char*)A +
      ((size_t)(mbase + (rg << 4) + srow) << 11) + (kgs << 6) + sbyte;
  const char* Bg = (const char*)Bw +
      ((size_t)(nbase + (rg << 4) + srow) << 11) + (kgs << 6) + sbyte;

  f32x4 acc[8][4] = {};
  f16x8 b[4][2];
  f16x8 aP[2][2];

  // prologue: A0(0) A1(0) B0(0) B1(0) B0(1) B1(1) A0(1)  (7 half-tiles, 14 loads/wave)
  STAGE_A(0, 0); STAGE_A(0, 1);
  STAGE_B(0, 0); STAGE_B(0, 1);
  STAGE_B(1, 0); STAGE_B(1, 1);
  STAGE_A(1, 0);
  VMW6;   // tile 0 resident; B0(1),B1(1),A0(1) in flight
  SB0(); __builtin_amdgcn_s_barrier(); SB0();

#pragma unroll 1
  for (int i = 0; i < 7; ++i) {        // tiles 0..13, steady state
    const int t = i << 1;
    TILE(t,     STAGE_A(t + 1, 1), STAGE_B(t + 2, 0), STAGE_B(t + 2, 1), STAGE_A(t + 2, 0), VMW6);
    TILE(t + 1, STAGE_A(t + 2, 1), STAGE_B(t + 3, 0), STAGE_B(t + 3, 1), STAGE_A(t + 3, 0), VMW6);
  }
  // tail: tiles 14,15 — stage only A1(15), then drain once
  TILE(14, STAGE_A(15, 1), NOP_, NOP_, NOP_, VMW0);
  TILE(15, NOP_, NOP_, NOP_, NOP_, NOP_);

  // epilogue: C/D layout col = lane&15, row = (lane>>4)*4 + j
  // wave rows: mf<4 -> half0 (wr*64 + mf*16), mf>=4 -> 128 + wr*64 + (mf-4)*16
  const int rl = (lane >> 4) << 2;
  const int cl = lane & 15;
  if (EPI == 0) {
    const int which = nbase >> 10;     // 0:Q 1:K 2:V (256-tile never straddles)
    const float* bias = (which == 0) ? bias0 : (which == 1) ? bias1 : bias2;
    _Float16* O = (which == 0) ? O0 : (which == 1) ? O1 : O2;
    const int cb = (nbase & 1023) + wcol;
#pragma unroll
    for (int mf = 0; mf < 8; mf++) {
      const int gm = mbase + ((mf < 4) ? 0 : 128) + wrow + ((mf & 3) << 4) + rl;
#pragma unroll
      for (int nf = 0; nf < 4; nf++) {
        const int gc = cb + (nf << 4) + cl;
        const float bz = bias[gc];
#pragma unroll
        for (int j = 0; j < 4; j++) {
          float v = acc[mf][nf][j] + bz;
          if (which < 2) v = (v > 0.f) ? (v + 1.f) : expf(v);  // elu(v)+1
          O[(size_t)(gm + j) * EE + gc] = (_Float16)v;
        }
      }
    }
  } else {
    const int cb = nbase + wcol;
#pragma unroll
    for (int mf = 0; mf < 8; mf++) {
      const int gm = mbase + ((mf < 4) ? 0 : 128) + wrow + ((mf & 3) << 4) + rl;
#pragma unroll
      for (int nf = 0; nf < 4; nf++) {
        const int gc = cb + (nf << 4) + cl;
        const float bz = bias0[gc];
#pragma unroll
        for (int j = 0; j < 4; j++)
          OF[(size_t)(gm + j) * EE + gc] = acc[mf][nf][j] + bz;
      }
    }
  }
}

#undef TILE
#undef PHASE
#undef RD_A
#undef RD_B
#undef STAGE_A
#undef STAGE_B
#undef STAGE_M

// ---------- stage 2: partial KV (K^T V) and partial K_sum, per (bh, s-chunk) ----------
__global__ __launch_bounds__(256) void kv_partial_kernel(const _Float16* __restrict__ Kh,
                                                         const _Float16* __restrict__ Vh,
                                                         float* __restrict__ kvpart,
                                                         float* __restrict__ ksump) {
  __shared__ __align__(16) _Float16 Ks[64 * 64];
  __shared__ __align__(16) _Float16 Vs[64 * 64];
  const int tid = threadIdx.x;
  const int wv = tid >> 6;
  const int bh = blockIdx.x;        // b*16 + h
  const int chunk = blockIdx.y;     // 16 chunks of 256 rows
  const int b = bh >> 4, h = bh & 15;
  const int td = tid >> 4, te = tid & 15;
  const int d0 = td * 4, e0 = te * 4;

  float kv[4][4] = {};
  float ks4[4] = {0.f, 0.f, 0.f, 0.f};

  for (int sub = 0; sub < 4; sub++) {
    const int s0 = chunk * 256 + sub * 64;
    __syncthreads();
    {
      const int g0 = tid, g1 = tid + 256;
      gload16((const char*)Kh + ((size_t)(b * SS + s0 + (g0 >> 3)) * EE + h * DD) * 2 + (g0 & 7) * 16,
              (char*)Ks + wv * 1024);
      gload16((const char*)Kh + ((size_t)(b * SS + s0 + (g1 >> 3)) * EE + h * DD) * 2 + (g1 & 7) * 16,
              (char*)Ks + 4096 + wv * 1024);
      gload16((const char*)Vh + ((size_t)(b * SS + s0 + (g0 >> 3)) * EE + h * DD) * 2 + (g0 & 7) * 16,
              (char*)Vs + wv * 1024);
      gload16((const char*)Vh + ((size_t)(b * SS + s0 + (g1 >> 3)) * EE + h * DD) * 2 + (g1 & 7) * 16,
              (char*)Vs + 4096 + wv * 1024);
    }
    __syncthreads();
#pragma unroll 8
    for (int s = 0; s < 64; s++) {
      f16x4 kk = *(const f16x4*)&Ks[s * 64 + d0];
      f16x4 vv = *(const f16x4*)&Vs[s * 64 + e0];
      float kf[4], vf[4];
#pragma unroll
      for (int i = 0; i < 4; i++) { kf[i] = (float)kk[i]; vf[i] = (float)vv[i]; }
#pragma unroll
      for (int i = 0; i < 4; i++)
#pragma unroll
        for (int j = 0; j < 4; j++) kv[i][j] += kf[i] * vf[j];
      if (te == 0) {
#pragma unroll
        for (int i = 0; i < 4; i++) ks4[i] += kf[i];
      }
    }
  }
  const size_t base = ((size_t)chunk * 64 + bh) * 4096;
#pragma unroll
  for (int i = 0; i < 4; i++)
#pragma unroll
    for (int j = 0; j < 4; j++) kvpart[base + (size_t)(d0 + i) * 64 + e0 + j] = kv[i][j];
  if (te == 0) {
#pragma unroll
    for (int i = 0; i < 4; i++) ksump[((size_t)chunk * 64 + bh) * 64 + d0 + i] = ks4[i];
  }
}

// ---------- stage 2b: reduce partials -> KV^T (fp16, [bh][e][d]) and K_sum (f32) ----------
__global__ __launch_bounds__(256) void kv_reduce_kernel(const float* __restrict__ kvpart,
                                                        const float* __restrict__ ksump,
                                                        _Float16* __restrict__ kvt,
                                                        float* __restrict__ ksum) {
  const int idx = blockIdx.x * 256 + threadIdx.x;
  if (blockIdx.x < 1024) {
    const int bh = idx >> 12;
    const int rem = idx & 4095;     // d*64 + e
    float s = 0.f;
#pragma unroll
    for (int c = 0; c < 16; c++) s += kvpart[((size_t)c * 64 + bh) * 4096 + rem];
    const int d = rem >> 6, e = rem & 63;
    kvt[(size_t)bh * 4096 + e * 64 + d] = (_Float16)s;
  } else {
    const int i2 = idx - 1024 * 256;  // 0..4095
    const int bh = i2 >> 6, d = i2 & 63;
    float s = 0.f;
#pragma unroll
    for (int c = 0; c < 16; c++) s += ksump[((size_t)c * 64 + bh) * 64 + d];
    ksum[i2] = s;
  }
}

// ---------- stage 3: attn[m][h*64+e] = Z * sum_d Q[m][d] * KV[d][e] ----------
__global__ __launch_bounds__(256) void attn_kernel(const _Float16* __restrict__ Qh,
                                                   const _Float16* __restrict__ kvt,
                                                   const float* __restrict__ ksum,
                                                   _Float16* __restrict__ attn) {
  __shared__ __align__(16) _Float16 Qs[64 * 64];
  __shared__ __align__(16) _Float16 KVs[64 * 64];
  __shared__ float ks_lds[64];
  __shared__ float dpart[4][64];
  __shared__ float zr[64];
  const int tid = threadIdx.x;
  const int lane = tid & 63;
  const int wv = tid >> 6;
  const int stile = blockIdx.x;     // 64 tiles of 64 rows
  const int bh = blockIdx.y;
  const int b = bh >> 4, h = bh & 15;
  const int m0 = b * SS + stile * 64;

  {
    const int g0 = tid, g1 = tid + 256;
    gload16((const char*)Qh + ((size_t)(m0 + (g0 >> 3)) * EE + h * DD) * 2 + (g0 & 7) * 16,
            (char*)Qs + wv * 1024);
    gload16((const char*)Qh + ((size_t)(m0 + (g1 >> 3)) * EE + h * DD) * 2 + (g1 & 7) * 16,
            (char*)Qs + 4096 + wv * 1024);
    gload16((const char*)kvt + (size_t)bh * 8192 + (size_t)g0 * 16, (char*)KVs + wv * 1024);
    gload16((const char*)kvt + (size_t)bh * 8192 + (size_t)g1 * 16, (char*)KVs + 4096 + wv * 1024);
  }
  if (tid < 64) ks_lds[tid] = ksum[bh * 64 + tid];
  __syncthreads();

  // denominator: Q[r]·K_sum, 4-way split over d
  {
    const int r = tid & 63, qd = tid >> 6;
    float p = 0.f;
#pragma unroll
    for (int i = 0; i < 16; i++) p += (float)Qs[r * 64 + qd * 16 + i] * ks_lds[qd * 16 + i];
    dpart[qd][r] = p;
  }
  __syncthreads();
  if (tid < 64) {
    float den = dpart[0][tid] + dpart[1][tid] + dpart[2][tid] + dpart[3][tid];
    zr[tid] = 1.f / (den + 1e-6f);
  }
  __syncthreads();

  // Q(64x64) @ KV(64x64): wave wv owns rows wv*16..wv*16+15
  f32x4 acc[4] = {};
  const int fr = lane & 15;
  const int kg = (lane >> 4) * 8;
#pragma unroll
  for (int kh = 0; kh < 2; kh++) {
    f16x8 a = *(const f16x8*)&Qs[(wv * 16 + fr) * 64 + kh * 32 + kg];
#pragma unroll
    for (int n = 0; n < 4; n++) {
      f16x8 b8 = *(const f16x8*)&KVs[(n * 16 + fr) * 64 + kh * 32 + kg];
      acc[n] = __builtin_amdgcn_mfma_f32_16x16x32_f16(a, b8, acc[n], 0, 0, 0);
    }
  }

  const int rl = (lane >> 4) * 4, cl = lane & 15;
#pragma unroll
  for (int n = 0; n < 4; n++)
#pragma unroll
    for (int j = 0; j < 4; j++) {
      const int r = wv * 16 + rl + j;
      float v = acc[n][j] * zr[r];
      attn[(size_t)(m0 + r) * EE + h * DD + n * 16 + cl] = (_Float16)v;
    }
}

// ---------- launch ----------
extern "C" void kernel_launch(void* const* d_in, const int* in_sizes, int n_in,
                              void* d_out, int out_size, void* d_ws, size_t ws_size,
                              hipStream_t stream) {
  const float* x  = (const float*)d_in[0];
  const float* Wq = (const float*)d_in[1];
  const float* bq = (const float*)d_in[2];
  const float* Wk = (const float*)d_in[3];
  const float* bk = (const float*)d_in[4];
  const float* Wv = (const float*)d_in[5];
  const float* bv = (const float*)d_in[6];
  const float* Wo = (const float*)d_in[7];
  const float* bo = (const float*)d_in[8];
  float* out = (float*)d_out;

  char* ws = (char*)d_ws;
  size_t off = 0;
  auto alloc = [&](size_t bytes) -> char* {
    char* p = ws + off;
    off += (bytes + 255) & ~(size_t)255;
    return p;
  };
  _Float16* xh    = (_Float16*)alloc((size_t)MM * EE * 2);      // 32 MB
  _Float16* wqkv  = (_Float16*)alloc((size_t)3 * EE * EE * 2);  // 6 MB
  _Float16* woh   = (_Float16*)alloc((size_t)EE * EE * 2);      // 2 MB
  _Float16* Qh    = (_Float16*)alloc((size_t)MM * EE * 2);      // 32 MB
  _Float16* Kh    = (_Float16*)alloc((size_t)MM * EE * 2);      // 32 MB
  _Float16* Vh    = (_Float16*)alloc((size_t)MM * EE * 2);      // 32 MB
  float*    kvpart= (float*)alloc((size_t)16 * 64 * 4096 * 4);  // 16 MB
  float*    ksump = (float*)alloc((size_t)16 * 64 * 64 * 4);    // 256 KB
  _Float16* kvt   = (_Float16*)alloc((size_t)64 * 4096 * 2);    // 512 KB
  float*    ksum  = (float*)alloc((size_t)64 * 64 * 4);         // 16 KB
  _Float16* attn  = xh;  // xh is dead after the QKV GEMM; reuse (stream-ordered)

  (void)in_sizes; (void)n_in; (void)out_size; (void)ws_size;

  conv_x_kernel<<<2048, 256, 0, stream>>>(x, xh, (MM * EE) / 4);
  conv_w_kernel<<<1024, 256, 0, stream>>>(Wq, Wk, Wv, Wo, wqkv, woh);
  // QKV projection: M=16384, N=3072, K=1024 -> 64x12 = 768 blocks (768%8==0)
  gemm256<0><<<768, 512, 0, stream>>>(xh, wqkv, bq, bk, bv, Qh, Kh, Vh, nullptr);
  kv_partial_kernel<<<dim3(64, 16), 256, 0, stream>>>(Kh, Vh, kvpart, ksump);
  kv_reduce_kernel<<<1040, 256, 0, stream>>>(kvpart, ksump, kvt, ksum);
  attn_kernel<<<dim3(64, 64), 256, 0, stream>>>(Qh, kvt, ksum, attn);
  // output projection: M=16384, N=1024, K=1024 -> 64x4 = 256 blocks
  gemm256<1><<<256, 512, 0, stream>>>(attn, woh, bo, nullptr, nullptr,
                                      nullptr, nullptr, nullptr, out);
}